// Round 5
// baseline (51809.564 us; speedup 1.0000x reference)
//
#include <hip/hip_runtime.h>
#include <math.h>

// ---------------------------------------------------------------------------
// FastFFTNet autoregressive sampler on MI355X — round 14: sleep dose-response.
// R13 post-mortem: presleep 3x127 gave -3.7ms (50.9->47.2ms) but FETCH stayed
// ~470MB -> poll pressure costs LATENCY at the MALL, not HBM bytes (FETCH is
// structural: write-allocate+victim of the 134KB/step store stream). VALUBusy
// 0.74->0.52% confirms sleeps engaged.
// R14: same mechanism, higher dose. Frontier presleep 3->4x s_sleep(127)
// (~13.6us of the ~21us dead window; floor own-work+sleep+discovery ~16.6us
// < expected ~21.5us step -> off critical path; 5 units would bind). Helper
// gate nap s_sleep(31)->s_sleep(127) (helpers run up to 31 steps ahead; gate
// block lasts a full ~23us step). Tap/Q1-idx spins stay tight (data long-
// published, ~1 poll). Timing-only: bit-exact by construction.
// If neutral: poll-pressure exhausted -> R15 pivots to in-block barrier
// reduction + Q10-inline partial logits.
//
// Blocks (53): 0 sampler | 1,2 L0A/L0B | 3..42 Q(layer j=1..10, k=0..3)
//              | 43..52 helper_j (past taps)
// ---------------------------------------------------------------------------

#define T_STEPS 2048
#define NBLK    53

typedef unsigned long long u64;
typedef float v64f __attribute__((ext_vector_type(64)));

// ws float offsets
#define OFF_EMBT   0           // tanh(emb_raw)           [256][256]
#define OFF_WPET   65536       // WV_present[0] @ emb^T   [class][256]
#define OFF_WVPET  131072      // WV_past[0]    @ emb^T   [class][256]
#define OFF_RINGS  196608      // ring_j (plain f32) at +512*((1<<j)-1)
#define OFF_TAPQ   1244672     // u64 pairs [10][32][256]
#define OFF_ZQ4    1408512     // u64 pairs [11][4][256] (layer0 uses slots 0,1)
#define OFF_XQ     1431040     // u64 pairs [11][256]    (x_j from Q0, j=1..10)
#define OFF_IDXQ   1436672     // one u64 pair
#define WS_FLOATS  1436736

#define FBAR(r)  (32*(r))      // init barriers; poison-safe monotone

// ---- agent-scope plain relaxed prims (proven coherence class) -------------
__device__ __forceinline__ float ldc(const float* p) {
  int v = __hip_atomic_load((const int*)p, __ATOMIC_RELAXED, __HIP_MEMORY_SCOPE_AGENT);
  return __int_as_float(v);
}
__device__ __forceinline__ void stc(float* p, float x) {
  __hip_atomic_store((int*)p, __float_as_int(x), __ATOMIC_RELAXED, __HIP_MEMORY_SCOPE_AGENT);
}
__device__ __forceinline__ u64 ldq(const u64* p) {
  return __hip_atomic_load(p, __ATOMIC_RELAXED, __HIP_MEMORY_SCOPE_AGENT);
}
__device__ __forceinline__ void stq(u64* p, float v, int tag) {
  u64 x = (u64)(unsigned)__float_as_int(v) | ((u64)(unsigned)tag << 32);
  __hip_atomic_store(p, x, __ATOMIC_RELAXED, __HIP_MEMORY_SCOPE_AGENT);
}
__device__ __forceinline__ int ptag(u64 q) { return (int)(q >> 32); }
__device__ __forceinline__ float pval(u64 q) { return __int_as_float((int)(unsigned)q); }

// ---- poll-pressure control: frontier waits are ~21us dead; sleep through
// ~13.6us of it, then tight-poll. Timing-only.
__device__ __forceinline__ void presleep() {
  __builtin_amdgcn_s_sleep(127);   // ~3.4us each at 2.4GHz
  __builtin_amdgcn_s_sleep(127);
  __builtin_amdgcn_s_sleep(127);
  __builtin_amdgcn_s_sleep(127);
}

// ---- R9 single-outstanding spins (proven class; R10 pipelining disproven)
__device__ __forceinline__ float spin_pair(const u64* p, int want) {
  int bud = 1 << 20; u64 q;
  do { q = ldq(p); } while (ptag(q) < want && --bud > 0);
  return pval(q);
}
__device__ __forceinline__ int spin_idx(const u64* p, int want) {
  int bud = 1 << 20; u64 q;
  do { q = ldq(p); } while (ptag(q) < want && --bud > 0);
  return __float_as_int(pval(q)) & 255;
}
__device__ __forceinline__ void spin2(const u64* p1, const u64* p2, int want,
                                      float& v1, float& v2) {
  int bud = 1 << 20; u64 q1, q2; bool ok;
  do {
    q1 = ldq(p1); q2 = ldq(p2);
    ok = (ptag(q1) >= want) & (ptag(q2) >= want);
  } while (!ok && --bud > 0);
  v1 = pval(q1); v2 = pval(q2);
}
__device__ __forceinline__ void spin5(const u64* p0, const u64* p1, const u64* p2,
                                      const u64* p3, const u64* p4, int want,
                                      float& v0, float& v1, float& v2, float& v3, float& v4) {
  int bud = 1 << 20; u64 q0, q1, q2, q3, q4; bool ok;
  do {
    q0 = ldq(p0); q1 = ldq(p1); q2 = ldq(p2); q3 = ldq(p3); q4 = ldq(p4);
    ok = (ptag(q0) >= want) & (ptag(q1) >= want) & (ptag(q2) >= want)
       & (ptag(q3) >= want) & (ptag(q4) >= want);
  } while (!ok && --bud > 0);
  v0 = pval(q0); v1 = pval(q1); v2 = pval(q2); v3 = pval(q3); v4 = pval(q4);
}
__device__ __forceinline__ void spin_tag2(const u64* p1, const u64* p2, int w1, int w2) {
  int bud = 1 << 18; u64 q1, q2; bool ok;
  do {
    q1 = ldq(p1); q2 = ldq(p2);
    ok = (ptag(q1) >= w1) & (ptag(q2) >= w2);
    if (!ok) __builtin_amdgcn_s_sleep(127);  // helper gates block a full step
  } while (!ok && --bud > 0);
}
// init-phase flag prims (proven)
__device__ __forceinline__ void wait1(int* f, int want) {
  int it = 0;
  while (__hip_atomic_load(f, __ATOMIC_RELAXED, __HIP_MEMORY_SCOPE_AGENT) < want) {
    if (++it > (1 << 22)) break;
  }
  (void)__hip_atomic_load(f, __ATOMIC_ACQUIRE, __HIP_MEMORY_SCOPE_AGENT);
}
__device__ __forceinline__ void post(int* f, int v) {
  __hip_atomic_store(f, v, __ATOMIC_RELEASE, __HIP_MEMORY_SCOPE_AGENT);
}

__global__ __launch_bounds__(512, 1)
void fftnet_kernel(const float* __restrict__ y, const float* __restrict__ samples,
                   const float* __restrict__ emb_raw, const float* __restrict__ condW,
                   const float* __restrict__ WV_past, const float* __restrict__ WV_present,
                   const float* __restrict__ W_o_w, const float* __restrict__ W_o_b,
                   const float* __restrict__ end_w, const float* __restrict__ end_b,
                   int* __restrict__ out, float* __restrict__ ws)
{
  const int tid = threadIdx.x;
  const int bid = blockIdx.x;
  int* iflags = (int*)(ws + WS_FLOATS);
  u64* zq4  = (u64*)(ws + OFF_ZQ4);
  u64* xq   = (u64*)(ws + OFF_XQ);
  u64* tq   = (u64*)(ws + OFF_TAPQ);
  u64* idxq = (u64*)(ws + OFF_IDXQ);

  __shared__ float s_x[256];
  __shared__ float s_h[256];
  __shared__ float s_p[1024];
  __shared__ float s_cond[2048];
  __shared__ float s_tap[64];
  __shared__ float s_m[320];
  __shared__ unsigned long long s_mask[8];

  // ---- init B: embt = tanh(emb_raw) ---------------------------------------
  for (int i = bid * 512 + tid; i < 65536; i += NBLK * 512)
    stc(ws + OFF_EMBT + i, tanhf(emb_raw[i]));
  __syncthreads();
  if (tid == 0) post(iflags + FBAR(bid), 1);
  if (tid < NBLK) wait1(iflags + FBAR(tid), 1);
  __syncthreads();

  // ---- init C: WPEt / WVP0Et tables ---------------------------------------
  for (int n = bid; n < 512; n += NBLK) {
    const float* wmat = (n < 256) ? WV_present : WV_past;  // layer-0 slice
    int cls = n & 255;
    int c = tid & 255, s2 = tid >> 8;
    float acc = 0.f;
    for (int k = 128 * s2; k < 128 * s2 + 128; ++k)
      acc += wmat[c * 256 + k] * ws[OFF_EMBT + cls * 256 + k];
    s_p[s2 * 256 + c] = acc;
    __syncthreads();
    if (tid < 256)
      stc(ws + ((n < 256) ? OFF_WPET : OFF_WVPET) + cls * 256 + tid, s_p[tid] + s_p[256 + tid]);
    __syncthreads();
  }
  __syncthreads();
  if (tid == 0) post(iflags + FBAR(bid), 2);
  if (tid < NBLK) wait1(iflags + FBAR(tid), 2);
  __syncthreads();
  __builtin_amdgcn_fence(__ATOMIC_ACQUIRE, "agent");   // invalidate stale L1
  __syncthreads();

  // =========================================================================
  if (bid == 0) {
    // ------------------------- sampler -------------------------------------
    const int c = tid & 255, s2 = tid >> 8;
    v64f we0;                               // first 64: register-resident
#pragma unroll
    for (int i = 0; i < 64; ++i) we0[i] = end_w[c * 256 + 128 * s2 + i];
    const float eb = end_b[c];
    const float b10 = W_o_b[10 * 256 + c];
    const u64* pz0 = zq4 + (10 * 4 + 0) * 256;
    const u64* pz1 = zq4 + (10 * 4 + 1) * 256;
    const u64* pz2 = zq4 + (10 * 4 + 2) * 256;
    const u64* pz3 = zq4 + (10 * 4 + 3) * 256;
    const u64* pxq = xq + 10 * 256;
    const int lane = tid & 63, w = tid >> 6;
    if (tid == 0) stq(idxq, __int_as_float(127), 1);

    for (int t = 0; t < T_STEPS; ++t) {
      float u = samples[t];
      // we1 prefetch (R12): issue before the sleep+spin so the L2 stream
      // completes during the dead wait.
      const float* ewp = end_w + c * 256 + 128 * s2 + 64;
      asm volatile("" : "+v"(ewp));
      ewp = (const float*)__builtin_assume_aligned(ewp, 16);
      v64f we1;
#pragma unroll
      for (int i = 0; i < 64; ++i) we1[i] = ewp[i];
      __builtin_amdgcn_sched_barrier(0);

      if (tid < 256) {
        if (t >= 2) presleep();             // ~13.6us of the ~21us dead wait
        float a, b, cc, d, r3;
        spin5(pz0 + tid, pz1 + tid, pz2 + tid, pz3 + tid, pxq + tid, t + 1, a, b, cc, d, r3);
        float s01 = a + b, s23 = cc + d;          // == zA, zB of R7 bitwise
        s_x[tid] = fmaxf(s01 + s23 + b10 + r3, 0.f);
      }
      __syncthreads();
      float acc = 0.f;
#pragma unroll
      for (int i = 0; i < 64; ++i) acc += we0[i] * s_x[128 * s2 + i];
#pragma unroll
      for (int i = 0; i < 64; ++i) acc += we1[i] * s_x[128 * s2 + 64 + i];
      s_p[s2 * 256 + c] = acc;
      __syncthreads();
      float logit = 0.f;
      if (tid < 256) logit = s_p[tid] + s_p[256 + tid] + eb;
      float vmax = (tid < 256) ? logit : -3.4e38f;
#pragma unroll
      for (int d2 = 32; d2 > 0; d2 >>= 1) vmax = fmaxf(vmax, __shfl_xor(vmax, d2, 64));
      if (lane == 0) s_m[280 + w] = vmax;
      __syncthreads();
      float mx = fmaxf(fmaxf(s_m[280], s_m[281]), fmaxf(s_m[282], s_m[283]));
      float e = (tid < 256) ? expf(logit - mx) : 0.f;
      float vs = e;
#pragma unroll
      for (int d2 = 32; d2 > 0; d2 >>= 1) vs += __shfl_xor(vs, d2, 64);
      if (lane == 0) s_m[288 + w] = vs;
      __syncthreads();
      float ssum = s_m[288] + s_m[289] + s_m[290] + s_m[291];
      float p = (tid < 256) ? (e / ssum) : 0.f;
      float v = p;
#pragma unroll
      for (int d2 = 1; d2 < 64; d2 <<= 1) {
        float o = __shfl_up(v, (unsigned)d2, 64);
        if (lane >= d2) v += o;
      }
      if (tid < 256 && lane == 63) s_m[256 + w] = v;
      __syncthreads();
      float offs = 0.f;
      if (tid < 256) for (int k = 0; k < w; ++k) offs += s_m[256 + k];
      float cum = v + offs;
      unsigned long long msk = __ballot(tid < 256 && (cum > u));
      if (lane == 0) s_mask[w] = msk;
      __syncthreads();
      if (tid == 0) {
        int idx = 0;
        for (int k = 0; k < 4; ++k) {
          unsigned long long m2 = s_mask[k];
          if (m2) { idx = k * 64 + (int)__builtin_ctzll(m2); break; }
        }
        stq(idxq, __int_as_float(idx), t + 2);
        out[t] = idx;
      }
      __syncthreads();
    }

  } else if (bid <= 2) {
    // ------------------------- L0A / L0B ------------------------------------
    const int side = bid - 1;              // 0: h[0:128), wo cols 0:128; 1: rest
    const int row = tid & 255, chunk = tid >> 8;   // chunk in {0,1}
    v64f wv;
#pragma unroll
    for (int i = 0; i < 64; ++i)
      wv[i] = W_o_w[row * 256 + side * 128 + chunk * 64 + i];
    for (int e = tid; e < 2048; e += 512) {
      int f = e >> 7, rr = e & 127;
      float a = 0.f;
      for (int q = 0; q < 80; ++q) a += condW[(side * 128 + rr) * 80 + q] * y[q * 16 + f];
      s_cond[f * 128 + rr] = a;
    }
    __syncthreads();
    u64* zout = zq4 + (0 * 4 + side) * 256;
    int pidx = 127;

    for (int t = 0; t < T_STEPS; ++t) {
      int idx = pidx;
      if (tid < 128) {
        float tapv = (t > 0) ? ws[OFF_WVPET + pidx * 256 + side * 128 + tid] : 0.f;
        if (t >= 2) presleep();             // idx(t) lands ~23us after our t-1
        idx = spin_idx(idxq, t + 1);
        float hv = s_cond[(t >> 7) * 128 + tid]
                 + ws[OFF_WPET + idx * 256 + side * 128 + tid] + tapv;
        s_h[tid] = fmaxf(hv, 0.f);
        if (tid == 0) s_m[300] = __int_as_float(idx);
      }
      __syncthreads();
      float acc = 0.f;
#pragma unroll
      for (int i = 0; i < 64; ++i) acc += wv[i] * s_h[64 * chunk + i];
      s_p[chunk * 256 + row] = acc;
      __syncthreads();
      if (tid < 256) stq(zout + tid, s_p[tid] + s_p[256 + tid], t + 1);
      pidx = (tid < 128) ? idx : __float_as_int(s_m[300]);
      __syncthreads();
    }

  } else if (bid <= 42) {
    // ------------------------- layer Qk (j = 1..10, k = 0..3) ---------------
    const int jj = 1 + ((bid - 3) >> 2);
    const int k  = (bid - 3) & 3;
    v64f wv;                                // wp frag (t<256) or wo frag (t>=256)
    if (tid < 256) {
      int r = tid & 63, s = tid >> 6;
#pragma unroll
      for (int i = 0; i < 64; ++i)
        wv[i] = WV_present[jj * 65536 + (64 * k + r) * 256 + 64 * s + i];
    } else {
      int row = tid - 256;
#pragma unroll
      for (int i = 0; i < 64; ++i)
        wv[i] = W_o_w[jj * 65536 + row * 256 + 64 * k + i];
    }
    const float bprev = W_o_b[(jj - 1) * 256 + (tid & 255)];
    for (int e = tid; e < 1024; e += 512) {
      int f = e >> 6, rr = e & 63;
      float a = 0.f;
      for (int q = 0; q < 80; ++q)
        a += condW[(jj * 256 + 64 * k + rr) * 80 + q] * y[q * 16 + f];
      s_cond[f * 64 + rr] = a;
    }
    __syncthreads();
    const int dj = 1 << jj, maskj = 2 * dj - 1;
    float* ringj = ws + OFF_RINGS + 512 * (dj - 1);
    const u64* pz0 = zq4 + ((jj - 1) * 4 + 0) * 256;
    const u64* pz1 = zq4 + ((jj - 1) * 4 + 1) * 256;
    const u64* pz2 = zq4 + ((jj - 1) * 4 + 2) * 256;
    const u64* pz3 = zq4 + ((jj - 1) * 4 + 3) * 256;
    const u64* pxp = xq + (jj - 1) * 256;
    u64* zout = zq4 + (jj * 4 + k) * 256;
    u64* xout = xq + jj * 256;
    const u64* ptap = tq + (jj - 1) * 32 * 256;

    for (int t = 0; t < T_STEPS; ++t) {
      const int want = t + 1;
      if (tid < 256) {
        float xv;
        if (t >= 2) presleep();             // input lands ~23us after our t-1
        if (jj == 1) {
          // idx (tag want) is long-published — near-instant; issue the EMBT
          // row gather, then wait on the z pair (gather hides under z-wait).
          int idx = spin_idx(idxq, want);
          float ev = ws[OFF_EMBT + idx * 256 + tid];
          float a, b;
          spin2(pz0 + tid, pz1 + tid, want, a, b);
          // x1 = relu((zA0+zB0) + b0 + emb[idx]) — same association as R9
          xv = fmaxf((a + b) + bprev + ev, 0.f);
        } else {
          float a, b, cc, d, xp;
          spin5(pz0 + tid, pz1 + tid, pz2 + tid, pz3 + tid, pxp + tid, want, a, b, cc, d, xp);
          float s01 = a + b, s23 = cc + d;   // == zA, zB bitwise
          xv = fmaxf(s01 + s23 + bprev + xp, 0.f);
        }
        s_x[tid] = xv;
        if (k == 0) stq(xout + tid, xv, want);        // early x publish
      } else if (tid >= 384 && tid < 448) {
        int l = tid - 384;
        s_tap[l] = spin_pair(ptap + (t & 31) * 256 + 64 * k + l, want);
      }
      __syncthreads();
      if (tid < 256) {
        int r = tid & 63, s = tid >> 6;
        float acc = 0.f;
#pragma unroll
        for (int i = 0; i < 64; ++i) acc += wv[i] * s_x[64 * s + i];
        s_p[s * 64 + r] = acc;
      } else if (k == 0) {
        int row = tid - 256;
        stc(ringj + (t & maskj) * 256 + row, s_x[row]);  // x_j history for taps
      }
      __syncthreads();
      if (tid < 64) {
        float hv = s_p[tid] + s_p[64 + tid] + s_p[128 + tid] + s_p[192 + tid]
                 + s_cond[(t >> 7) * 64 + tid] + s_tap[tid];
        s_h[tid] = fmaxf(hv, 0.f);
      }
      __syncthreads();
      if (tid >= 256) {
        int row = tid - 256;
        float acc = 0.f;
#pragma unroll
        for (int i = 0; i < 64; ++i) acc += wv[i] * s_h[i];
        if (k == 0)
          __builtin_amdgcn_fence(__ATOMIC_RELEASE, "agent");  // ring before z tag
        stq(zout + row, acc, want);
      }
      __syncthreads();
    }

  } else {
    // ------------------------- tap helpers (j = 1..10) ----------------------
    const int j = bid - 42;
    const int dj = 1 << j, maskj = 2 * dj - 1;
    v64f wq0, wq1;
    { int r = tid & 255, s2 = tid >> 8;
#pragma unroll
      for (int i = 0; i < 64; ++i) wq0[i] = WV_past[j * 65536 + r * 256 + 128 * s2 + i];
#pragma unroll
      for (int i = 0; i < 64; ++i) wq1[i] = WV_past[j * 65536 + r * 256 + 128 * s2 + 64 + i]; }
    float* ringj = ws + OFF_RINGS + 512 * (dj - 1);
    u64* tapj = tq + (j - 1) * 32 * 256;
    const u64* z0 = zq4 + (j * 4 + 0) * 256;

    for (int t = 0; t < T_STEPS; ++t) {
      // gates: ring(t-dj) visible via z_{j,0} tag (fence-ordered, same thread);
      // slot reuse: consumer Q_{e>>6} past step t-32 via its zout tag.
      int g0 = t - 31;
      if (t >= dj && t - dj + 1 > g0) g0 = t - dj + 1;
      int gk = t - 31;
      if (tid < 256 && (g0 >= 1 || gk >= 1)) {
        const u64* zk = zq4 + (j * 4 + (tid >> 6)) * 256;
        spin_tag2(z0 + tid, zk + tid, g0, gk);
      }
      float tapv = 0.f;
      if (t >= dj) {
        if (tid < 256) s_x[tid] = ldc(ringj + ((t - dj) & maskj) * 256 + tid);
        __syncthreads();
        int r = tid & 255, s2 = tid >> 8;
        float acc = 0.f;
#pragma unroll
        for (int i = 0; i < 64; ++i) acc += wq0[i] * s_x[128 * s2 + i];
#pragma unroll
        for (int i = 0; i < 64; ++i) acc += wq1[i] * s_x[128 * s2 + 64 + i];
        s_p[s2 * 256 + r] = acc;
        __syncthreads();
        if (tid < 256) tapv = s_p[tid] + s_p[256 + tid];
      }
      if (tid < 256) stq(tapj + (t & 31) * 256 + tid, tapv, t + 1);
      __syncthreads();
    }
  }
}

extern "C" void kernel_launch(void* const* d_in, const int* in_sizes, int n_in,
                              void* d_out, int out_size, void* d_ws, size_t ws_size,
                              hipStream_t stream) {
  const float* y       = (const float*)d_in[0];
  const float* samples = (const float*)d_in[1];
  const float* emb_raw = (const float*)d_in[2];
  const float* condW   = (const float*)d_in[3];
  const float* WV_past = (const float*)d_in[4];
  const float* WV_pres = (const float*)d_in[5];
  const float* W_o_w   = (const float*)d_in[6];
  const float* W_o_b   = (const float*)d_in[7];
  const float* end_w   = (const float*)d_in[8];
  const float* end_b   = (const float*)d_in[9];
  (void)in_sizes; (void)n_in; (void)out_size; (void)ws_size;
  hipLaunchKernelGGL(fftnet_kernel, dim3(NBLK), dim3(512), 0, stream,
                     y, samples, emb_raw, condW, WV_past, WV_pres,
                     W_o_w, W_o_b, end_w, end_b, (int*)d_out, (float*)d_ws);
}

// Round 6
// 51702.734 us; speedup vs baseline: 1.0021x; 1.0021x over previous
//
#include <hip/hip_runtime.h>
#include <math.h>

// ---------------------------------------------------------------------------
// FastFFTNet autoregressive sampler on MI355X — round 15.
// R14 post-mortem: 4th frontier sleep unit REGRESSED (47.2->51.8ms): sleep
// crossed input arrival. s_sleep counts SHADER clocks; at 0.4% VALUBusy the
// chip downclocks and wall-time/unit stretches -> fixed dose is chasing a
// clock-dependent target. Helper-nap change was provably harmless (taps are
// published a full chain-loop before consumption).
// R15: (a) ADAPTIVE pre-sleep: per-block dose u (init 3, clamp [0,6]) in
// LDS; tid0 counts poll iters of the counted spin: it<=1 -> u-- (late/edge),
// it>=8 -> u++ (>~6us residual polling). Converges to wake 1-6 polls early,
// auto-tracking clock state. Helpers back to proven s_sleep(31).
// (b) BARRIER FUSION in L0+Q (11 serial segments): remap wp-dot so a row's
// 4 chunk partials sit in 4 adjacent lanes of one wave (r=tid>>2,s=tid&3);
// combine via 3 __shfl in exact left-fold ((p0+p1)+p2)+p3 == old
// s_p[tid]+s_p[64+tid]+s_p[128+tid]+s_p[192+tid]; each 64-MAC chain keeps
// its exact operand sequence -> bit-identical. Q: 4->3 barriers/step;
// L0 (2-partial fold): 3->2. Sampler untouched (association frozen).
//
// Blocks (53): 0 sampler | 1,2 L0A/L0B | 3..42 Q(layer j=1..10, k=0..3)
//              | 43..52 helper_j (past taps)
// ---------------------------------------------------------------------------

#define T_STEPS 2048
#define NBLK    53

typedef unsigned long long u64;
typedef float v64f __attribute__((ext_vector_type(64)));

// ws float offsets
#define OFF_EMBT   0           // tanh(emb_raw)           [256][256]
#define OFF_WPET   65536       // WV_present[0] @ emb^T   [class][256]
#define OFF_WVPET  131072      // WV_past[0]    @ emb^T   [class][256]
#define OFF_RINGS  196608      // ring_j (plain f32) at +512*((1<<j)-1)
#define OFF_TAPQ   1244672     // u64 pairs [10][32][256]
#define OFF_ZQ4    1408512     // u64 pairs [11][4][256] (layer0 uses slots 0,1)
#define OFF_XQ     1431040     // u64 pairs [11][256]    (x_j from Q0, j=1..10)
#define OFF_IDXQ   1436672     // one u64 pair
#define WS_FLOATS  1436736

#define FBAR(r)  (32*(r))      // init barriers; poison-safe monotone

// ---- agent-scope plain relaxed prims (proven coherence class) -------------
__device__ __forceinline__ float ldc(const float* p) {
  int v = __hip_atomic_load((const int*)p, __ATOMIC_RELAXED, __HIP_MEMORY_SCOPE_AGENT);
  return __int_as_float(v);
}
__device__ __forceinline__ void stc(float* p, float x) {
  __hip_atomic_store((int*)p, __float_as_int(x), __ATOMIC_RELAXED, __HIP_MEMORY_SCOPE_AGENT);
}
__device__ __forceinline__ u64 ldq(const u64* p) {
  return __hip_atomic_load(p, __ATOMIC_RELAXED, __HIP_MEMORY_SCOPE_AGENT);
}
__device__ __forceinline__ void stq(u64* p, float v, int tag) {
  u64 x = (u64)(unsigned)__float_as_int(v) | ((u64)(unsigned)tag << 32);
  __hip_atomic_store(p, x, __ATOMIC_RELAXED, __HIP_MEMORY_SCOPE_AGENT);
}
__device__ __forceinline__ int ptag(u64 q) { return (int)(q >> 32); }
__device__ __forceinline__ float pval(u64 q) { return __int_as_float((int)(unsigned)q); }

__device__ __forceinline__ void presleep_n(int n) {
  for (int i = 0; i < n; ++i) __builtin_amdgcn_s_sleep(127);  // ~3.4us @2.4GHz
}
// adaptive-dose update (tid0): it<=1 late/edge -> back off; it>=8 -> extend.
__device__ __forceinline__ int adapt_u(int uu, int it, int t) {
  if (t >= 2) {
    if (it <= 1 && uu > 0) --uu;
    else if (it >= 8 && uu < 6) ++uu;
  }
  return uu;
}

// ---- R9 single-outstanding spins (proven class) ---------------------------
__device__ __forceinline__ float spin_pair(const u64* p, int want) {
  int bud = 1 << 20; u64 q;
  do { q = ldq(p); } while (ptag(q) < want && --bud > 0);
  return pval(q);
}
__device__ __forceinline__ int spin_idx(const u64* p, int want) {
  int bud = 1 << 20; u64 q;
  do { q = ldq(p); } while (ptag(q) < want && --bud > 0);
  return __float_as_int(pval(q)) & 255;
}
__device__ __forceinline__ int spin_idxc(const u64* p, int want, int& it) {
  int bud = 1 << 20; u64 q; it = 0;
  do { q = ldq(p); ++it; } while (ptag(q) < want && --bud > 0);
  return __float_as_int(pval(q)) & 255;
}
__device__ __forceinline__ void spin2c(const u64* p1, const u64* p2, int want,
                                       float& v1, float& v2, int& it) {
  int bud = 1 << 20; u64 q1, q2; bool ok; it = 0;
  do {
    q1 = ldq(p1); q2 = ldq(p2); ++it;
    ok = (ptag(q1) >= want) & (ptag(q2) >= want);
  } while (!ok && --bud > 0);
  v1 = pval(q1); v2 = pval(q2);
}
__device__ __forceinline__ void spin5c(const u64* p0, const u64* p1, const u64* p2,
                                       const u64* p3, const u64* p4, int want,
                                       float& v0, float& v1, float& v2, float& v3,
                                       float& v4, int& it) {
  int bud = 1 << 20; u64 q0, q1, q2, q3, q4; bool ok; it = 0;
  do {
    q0 = ldq(p0); q1 = ldq(p1); q2 = ldq(p2); q3 = ldq(p3); q4 = ldq(p4); ++it;
    ok = (ptag(q0) >= want) & (ptag(q1) >= want) & (ptag(q2) >= want)
       & (ptag(q3) >= want) & (ptag(q4) >= want);
  } while (!ok && --bud > 0);
  v0 = pval(q0); v1 = pval(q1); v2 = pval(q2); v3 = pval(q3); v4 = pval(q4);
}
__device__ __forceinline__ void spin_tag2(const u64* p1, const u64* p2, int w1, int w2) {
  int bud = 1 << 18; u64 q1, q2; bool ok;
  do {
    q1 = ldq(p1); q2 = ldq(p2);
    ok = (ptag(q1) >= w1) & (ptag(q2) >= w2);
    if (!ok) __builtin_amdgcn_s_sleep(31);   // proven R13 helper nap
  } while (!ok && --bud > 0);
}
// init-phase flag prims (proven)
__device__ __forceinline__ void wait1(int* f, int want) {
  int it = 0;
  while (__hip_atomic_load(f, __ATOMIC_RELAXED, __HIP_MEMORY_SCOPE_AGENT) < want) {
    if (++it > (1 << 22)) break;
  }
  (void)__hip_atomic_load(f, __ATOMIC_ACQUIRE, __HIP_MEMORY_SCOPE_AGENT);
}
__device__ __forceinline__ void post(int* f, int v) {
  __hip_atomic_store(f, v, __ATOMIC_RELEASE, __HIP_MEMORY_SCOPE_AGENT);
}

__global__ __launch_bounds__(512, 1)
void fftnet_kernel(const float* __restrict__ y, const float* __restrict__ samples,
                   const float* __restrict__ emb_raw, const float* __restrict__ condW,
                   const float* __restrict__ WV_past, const float* __restrict__ WV_present,
                   const float* __restrict__ W_o_w, const float* __restrict__ W_o_b,
                   const float* __restrict__ end_w, const float* __restrict__ end_b,
                   int* __restrict__ out, float* __restrict__ ws)
{
  const int tid = threadIdx.x;
  const int bid = blockIdx.x;
  int* iflags = (int*)(ws + WS_FLOATS);
  u64* zq4  = (u64*)(ws + OFF_ZQ4);
  u64* xq   = (u64*)(ws + OFF_XQ);
  u64* tq   = (u64*)(ws + OFF_TAPQ);
  u64* idxq = (u64*)(ws + OFF_IDXQ);

  __shared__ float s_x[256];
  __shared__ float s_h[256];
  __shared__ float s_p[1024];
  __shared__ float s_cond[2048];
  __shared__ float s_tap[64];
  __shared__ float s_m[320];
  __shared__ unsigned long long s_mask[8];

  // ---- init B: embt = tanh(emb_raw) ---------------------------------------
  for (int i = bid * 512 + tid; i < 65536; i += NBLK * 512)
    stc(ws + OFF_EMBT + i, tanhf(emb_raw[i]));
  __syncthreads();
  if (tid == 0) post(iflags + FBAR(bid), 1);
  if (tid < NBLK) wait1(iflags + FBAR(tid), 1);
  __syncthreads();

  // ---- init C: WPEt / WVP0Et tables ---------------------------------------
  for (int n = bid; n < 512; n += NBLK) {
    const float* wmat = (n < 256) ? WV_present : WV_past;  // layer-0 slice
    int cls = n & 255;
    int c = tid & 255, s2 = tid >> 8;
    float acc = 0.f;
    for (int k = 128 * s2; k < 128 * s2 + 128; ++k)
      acc += wmat[c * 256 + k] * ws[OFF_EMBT + cls * 256 + k];
    s_p[s2 * 256 + c] = acc;
    __syncthreads();
    if (tid < 256)
      stc(ws + ((n < 256) ? OFF_WPET : OFF_WVPET) + cls * 256 + tid, s_p[tid] + s_p[256 + tid]);
    __syncthreads();
  }
  __syncthreads();
  if (tid == 0) post(iflags + FBAR(bid), 2);
  if (tid < NBLK) wait1(iflags + FBAR(tid), 2);
  __syncthreads();
  __builtin_amdgcn_fence(__ATOMIC_ACQUIRE, "agent");   // invalidate stale L1
  __syncthreads();

  // =========================================================================
  if (bid == 0) {
    // ------------------------- sampler -------------------------------------
    const int c = tid & 255, s2 = tid >> 8;
    v64f we0;                               // first 64: register-resident
#pragma unroll
    for (int i = 0; i < 64; ++i) we0[i] = end_w[c * 256 + 128 * s2 + i];
    const float eb = end_b[c];
    const float b10 = W_o_b[10 * 256 + c];
    const u64* pz0 = zq4 + (10 * 4 + 0) * 256;
    const u64* pz1 = zq4 + (10 * 4 + 1) * 256;
    const u64* pz2 = zq4 + (10 * 4 + 2) * 256;
    const u64* pz3 = zq4 + (10 * 4 + 3) * 256;
    const u64* pxq = xq + 10 * 256;
    const int lane = tid & 63, w = tid >> 6;
    if (tid == 0) { stq(idxq, __int_as_float(127), 1); s_m[301] = __int_as_float(3); }
    __syncthreads();

    for (int t = 0; t < T_STEPS; ++t) {
      float u = samples[t];
      // we1 prefetch (R12): issue before the sleep+spin so the L2 stream
      // completes during the dead wait.
      const float* ewp = end_w + c * 256 + 128 * s2 + 64;
      asm volatile("" : "+v"(ewp));
      ewp = (const float*)__builtin_assume_aligned(ewp, 16);
      v64f we1;
#pragma unroll
      for (int i = 0; i < 64; ++i) we1[i] = ewp[i];
      __builtin_amdgcn_sched_barrier(0);

      if (tid < 256) {
        int uu = __float_as_int(s_m[301]);
        if (t >= 2) presleep_n(uu);
        float a, b, cc, d, r3; int it;
        spin5c(pz0 + tid, pz1 + tid, pz2 + tid, pz3 + tid, pxq + tid, t + 1,
               a, b, cc, d, r3, it);
        if (tid == 0) s_m[301] = __int_as_float(adapt_u(uu, it, t));
        float s01 = a + b, s23 = cc + d;          // == zA, zB of R7 bitwise
        s_x[tid] = fmaxf(s01 + s23 + b10 + r3, 0.f);
      }
      __syncthreads();
      float acc = 0.f;
#pragma unroll
      for (int i = 0; i < 64; ++i) acc += we0[i] * s_x[128 * s2 + i];
#pragma unroll
      for (int i = 0; i < 64; ++i) acc += we1[i] * s_x[128 * s2 + 64 + i];
      s_p[s2 * 256 + c] = acc;
      __syncthreads();
      float logit = 0.f;
      if (tid < 256) logit = s_p[tid] + s_p[256 + tid] + eb;
      float vmax = (tid < 256) ? logit : -3.4e38f;
#pragma unroll
      for (int d2 = 32; d2 > 0; d2 >>= 1) vmax = fmaxf(vmax, __shfl_xor(vmax, d2, 64));
      if (lane == 0) s_m[280 + w] = vmax;
      __syncthreads();
      float mx = fmaxf(fmaxf(s_m[280], s_m[281]), fmaxf(s_m[282], s_m[283]));
      float e = (tid < 256) ? expf(logit - mx) : 0.f;
      float vs = e;
#pragma unroll
      for (int d2 = 32; d2 > 0; d2 >>= 1) vs += __shfl_xor(vs, d2, 64);
      if (lane == 0) s_m[288 + w] = vs;
      __syncthreads();
      float ssum = s_m[288] + s_m[289] + s_m[290] + s_m[291];
      float p = (tid < 256) ? (e / ssum) : 0.f;
      float v = p;
#pragma unroll
      for (int d2 = 1; d2 < 64; d2 <<= 1) {
        float o = __shfl_up(v, (unsigned)d2, 64);
        if (lane >= d2) v += o;
      }
      if (tid < 256 && lane == 63) s_m[256 + w] = v;
      __syncthreads();
      float offs = 0.f;
      if (tid < 256) for (int k = 0; k < w; ++k) offs += s_m[256 + k];
      float cum = v + offs;
      unsigned long long msk = __ballot(tid < 256 && (cum > u));
      if (lane == 0) s_mask[w] = msk;
      __syncthreads();
      if (tid == 0) {
        int idx = 0;
        for (int k = 0; k < 4; ++k) {
          unsigned long long m2 = s_mask[k];
          if (m2) { idx = k * 64 + (int)__builtin_ctzll(m2); break; }
        }
        stq(idxq, __int_as_float(idx), t + 2);
        out[t] = idx;
      }
      __syncthreads();
    }

  } else if (bid <= 2) {
    // ------------------------- L0A / L0B ------------------------------------
    // Fused: row's 2 chunk partials in adjacent lanes; combine via 1 shfl in
    // exact order (p0+p1) == old s_p[tid]+s_p[256+tid]. 3 -> 2 barriers.
    const int side = bid - 1;              // 0: h[0:128), wo cols 0:128; 1: rest
    const int row = tid >> 1, chunk = tid & 1;
    v64f wv;
#pragma unroll
    for (int i = 0; i < 64; ++i)
      wv[i] = W_o_w[row * 256 + side * 128 + chunk * 64 + i];
    for (int e = tid; e < 2048; e += 512) {
      int f = e >> 7, rr = e & 127;
      float a = 0.f;
      for (int q = 0; q < 80; ++q) a += condW[(side * 128 + rr) * 80 + q] * y[q * 16 + f];
      s_cond[f * 128 + rr] = a;
    }
    if (tid == 0) s_m[301] = __int_as_float(3);
    __syncthreads();
    u64* zout = zq4 + (0 * 4 + side) * 256;
    int pidx = 127;                        // tid<128 only

    for (int t = 0; t < T_STEPS; ++t) {
      if (tid < 128) {
        float tapv = (t > 0) ? ws[OFF_WVPET + pidx * 256 + side * 128 + tid] : 0.f;
        int uu = __float_as_int(s_m[301]);
        if (t >= 2) presleep_n(uu);
        int it;
        int idx = spin_idxc(idxq, t + 1, it);
        if (tid == 0) s_m[301] = __int_as_float(adapt_u(uu, it, t));
        float hv = s_cond[(t >> 7) * 128 + tid]
                 + ws[OFF_WPET + idx * 256 + side * 128 + tid] + tapv;
        s_h[tid] = fmaxf(hv, 0.f);
        pidx = idx;
      }
      __syncthreads();
      float acc = 0.f;
#pragma unroll
      for (int i = 0; i < 64; ++i) acc += wv[i] * s_h[64 * chunk + i];
      {
        int lb = (tid & 63) & ~1;
        float o = __shfl(acc, lb + 1, 64);
        if (chunk == 0) stq(zout + row, acc + o, t + 1);  // == s_p[tid]+s_p[256+tid]
      }
      __syncthreads();
    }

  } else if (bid <= 42) {
    // ------------------------- layer Qk (j = 1..10, k = 0..3) ---------------
    // Fused: wp-dot remapped r=tid>>2, s=tid&3 -> row's 4 partials in 4
    // adjacent lanes; combine via 3 shfl in exact left-fold
    // ((p0+p1)+p2)+p3 == old s_p[tid]+s_p[64+tid]+s_p[128+tid]+s_p[192+tid].
    // 4 -> 3 barriers.
    const int jj = 1 + ((bid - 3) >> 2);
    const int k  = (bid - 3) & 3;
    v64f wv;                                // wp frag (t<256) or wo frag (t>=256)
    if (tid < 256) {
      int r = tid >> 2, s = tid & 3;
#pragma unroll
      for (int i = 0; i < 64; ++i)
        wv[i] = WV_present[jj * 65536 + (64 * k + r) * 256 + 64 * s + i];
    } else {
      int row = tid - 256;
#pragma unroll
      for (int i = 0; i < 64; ++i)
        wv[i] = W_o_w[jj * 65536 + row * 256 + 64 * k + i];
    }
    const float bprev = W_o_b[(jj - 1) * 256 + (tid & 255)];
    for (int e = tid; e < 1024; e += 512) {
      int f = e >> 6, rr = e & 63;
      float a = 0.f;
      for (int q = 0; q < 80; ++q)
        a += condW[(jj * 256 + 64 * k + rr) * 80 + q] * y[q * 16 + f];
      s_cond[f * 64 + rr] = a;
    }
    if (tid == 0) s_m[301] = __int_as_float(3);
    __syncthreads();
    const int dj = 1 << jj, maskj = 2 * dj - 1;
    float* ringj = ws + OFF_RINGS + 512 * (dj - 1);
    const u64* pz0 = zq4 + ((jj - 1) * 4 + 0) * 256;
    const u64* pz1 = zq4 + ((jj - 1) * 4 + 1) * 256;
    const u64* pz2 = zq4 + ((jj - 1) * 4 + 2) * 256;
    const u64* pz3 = zq4 + ((jj - 1) * 4 + 3) * 256;
    const u64* pxp = xq + (jj - 1) * 256;
    u64* zout = zq4 + (jj * 4 + k) * 256;
    u64* xout = xq + jj * 256;
    const u64* ptap = tq + (jj - 1) * 32 * 256;

    for (int t = 0; t < T_STEPS; ++t) {
      const int want = t + 1;
      if (tid < 256) {
        float xv;
        int uu = __float_as_int(s_m[301]);
        if (t >= 2) presleep_n(uu);
        int it;
        if (jj == 1) {
          // idx long-published -> near-instant; issue EMBT gather, then wait
          // on the z pair (gather hides under z-wait).
          int idx = spin_idx(idxq, want);
          float ev = ws[OFF_EMBT + idx * 256 + tid];
          float a, b;
          spin2c(pz0 + tid, pz1 + tid, want, a, b, it);
          // x1 = relu((zA0+zB0) + b0 + emb[idx]) — same association as R9
          xv = fmaxf((a + b) + bprev + ev, 0.f);
        } else {
          float a, b, cc, d, xp;
          spin5c(pz0 + tid, pz1 + tid, pz2 + tid, pz3 + tid, pxp + tid, want,
                 a, b, cc, d, xp, it);
          float s01 = a + b, s23 = cc + d;   // == zA, zB bitwise
          xv = fmaxf(s01 + s23 + bprev + xp, 0.f);
        }
        if (tid == 0) s_m[301] = __int_as_float(adapt_u(uu, it, t));
        s_x[tid] = xv;
        if (k == 0) stq(xout + tid, xv, want);        // early x publish
      } else if (tid >= 384 && tid < 448) {
        int l = tid - 384;
        s_tap[l] = spin_pair(ptap + (t & 31) * 256 + 64 * k + l, want);
      }
      __syncthreads();
      if (tid < 256) {
        int r = tid >> 2, s = tid & 3;
        float acc = 0.f;
#pragma unroll
        for (int i = 0; i < 64; ++i) acc += wv[i] * s_x[64 * s + i];
        int lb = (tid & 63) & ~3;
        float p1 = __shfl(acc, lb + 1, 64);
        float p2 = __shfl(acc, lb + 2, 64);
        float p3 = __shfl(acc, lb + 3, 64);
        if (s == 0) {
          // ((p0+p1)+p2)+p3 + cond + tap — exact old phase-C association
          float hv = ((acc + p1) + p2) + p3
                   + s_cond[(t >> 7) * 64 + r] + s_tap[r];
          s_h[r] = fmaxf(hv, 0.f);
        }
      } else if (k == 0) {
        int row = tid - 256;
        stc(ringj + (t & maskj) * 256 + row, s_x[row]);  // x_j history for taps
      }
      __syncthreads();
      if (tid >= 256) {
        int row = tid - 256;
        float acc = 0.f;
#pragma unroll
        for (int i = 0; i < 64; ++i) acc += wv[i] * s_h[i];
        if (k == 0)
          __builtin_amdgcn_fence(__ATOMIC_RELEASE, "agent");  // ring before z tag
        stq(zout + row, acc, want);
      }
      __syncthreads();
    }

  } else {
    // ------------------------- tap helpers (j = 1..10) ----------------------
    const int j = bid - 42;
    const int dj = 1 << j, maskj = 2 * dj - 1;
    v64f wq0, wq1;
    { int r = tid & 255, s2 = tid >> 8;
#pragma unroll
      for (int i = 0; i < 64; ++i) wq0[i] = WV_past[j * 65536 + r * 256 + 128 * s2 + i];
#pragma unroll
      for (int i = 0; i < 64; ++i) wq1[i] = WV_past[j * 65536 + r * 256 + 128 * s2 + 64 + i]; }
    float* ringj = ws + OFF_RINGS + 512 * (dj - 1);
    u64* tapj = tq + (j - 1) * 32 * 256;
    const u64* z0 = zq4 + (j * 4 + 0) * 256;

    for (int t = 0; t < T_STEPS; ++t) {
      // gates: ring(t-dj) visible via z_{j,0} tag (fence-ordered, same thread);
      // slot reuse: consumer Q_{e>>6} past step t-32 via its zout tag.
      int g0 = t - 31;
      if (t >= dj && t - dj + 1 > g0) g0 = t - dj + 1;
      int gk = t - 31;
      if (tid < 256 && (g0 >= 1 || gk >= 1)) {
        const u64* zk = zq4 + (j * 4 + (tid >> 6)) * 256;
        spin_tag2(z0 + tid, zk + tid, g0, gk);
      }
      float tapv = 0.f;
      if (t >= dj) {
        if (tid < 256) s_x[tid] = ldc(ringj + ((t - dj) & maskj) * 256 + tid);
        __syncthreads();
        int r = tid & 255, s2 = tid >> 8;
        float acc = 0.f;
#pragma unroll
        for (int i = 0; i < 64; ++i) acc += wq0[i] * s_x[128 * s2 + i];
#pragma unroll
        for (int i = 0; i < 64; ++i) acc += wq1[i] * s_x[128 * s2 + 64 + i];
        s_p[s2 * 256 + r] = acc;
        __syncthreads();
        if (tid < 256) tapv = s_p[tid] + s_p[256 + tid];
      }
      if (tid < 256) stq(tapj + (t & 31) * 256 + tid, tapv, t + 1);
      __syncthreads();
    }
  }
}

extern "C" void kernel_launch(void* const* d_in, const int* in_sizes, int n_in,
                              void* d_out, int out_size, void* d_ws, size_t ws_size,
                              hipStream_t stream) {
  const float* y       = (const float*)d_in[0];
  const float* samples = (const float*)d_in[1];
  const float* emb_raw = (const float*)d_in[2];
  const float* condW   = (const float*)d_in[3];
  const float* WV_past = (const float*)d_in[4];
  const float* WV_pres = (const float*)d_in[5];
  const float* W_o_w   = (const float*)d_in[6];
  const float* W_o_b   = (const float*)d_in[7];
  const float* end_w   = (const float*)d_in[8];
  const float* end_b   = (const float*)d_in[9];
  (void)in_sizes; (void)n_in; (void)out_size; (void)ws_size;
  hipLaunchKernelGGL(fftnet_kernel, dim3(NBLK), dim3(512), 0, stream,
                     y, samples, emb_raw, condW, WV_past, WV_pres,
                     W_o_w, W_o_b, end_w, end_b, (int*)d_out, (float*)d_ws);
}

// Round 7
// 49000.113 us; speedup vs baseline: 1.0573x; 1.0552x over previous
//
#include <hip/hip_runtime.h>
#include <math.h>

// ---------------------------------------------------------------------------
// FastFFTNet autoregressive sampler on MI355X — round 16.
// R15 post-mortem (51.7ms, +4.5 vs R13): two defects. (1) fused wp-dot read
// s_x[64*s+i] with s varying IN-wave: 64*s = 0 mod 32 -> 4 addresses on ONE
// bank = 4-way LDS conflict every MAC (SQ_LDS_BANK_CONFLICT 0 -> 6.5e7).
// (2) adaptive sleep converges to the arrival EDGE; late wake stalls the
// chain ~1.7us/event (asymmetric penalty) -> edge-seeking is wrong by design.
// R16: revert sleep to R13's proven fixed 3x s_sleep(127) (helper nap 31);
// KEEP the Q barrier fusion but stage x in padded s_xp stride 72 (8 mod 32):
// writer banks 8w+l, reader addresses 72s+i -> banks (8s+i)%32 all distinct
// -> conflict-free broadcast. FMA chains + ((p0+p1)+p2)+p3 shfl fold remain
// operand-identical to R9 -> bit-exact. Single delta vs R13 = conflict-free
// fusion. Signature: BANK_CONFLICT -> ~0. If dur stays ~47: barriers were
// hidden -> R17 pivots to hop-count.
//
// Blocks (53): 0 sampler | 1,2 L0A/L0B | 3..42 Q(layer j=1..10, k=0..3)
//              | 43..52 helper_j (past taps)
// ---------------------------------------------------------------------------

#define T_STEPS 2048
#define NBLK    53

typedef unsigned long long u64;
typedef float v64f __attribute__((ext_vector_type(64)));

// ws float offsets
#define OFF_EMBT   0           // tanh(emb_raw)           [256][256]
#define OFF_WPET   65536       // WV_present[0] @ emb^T   [class][256]
#define OFF_WVPET  131072      // WV_past[0]    @ emb^T   [class][256]
#define OFF_RINGS  196608      // ring_j (plain f32) at +512*((1<<j)-1)
#define OFF_TAPQ   1244672     // u64 pairs [10][32][256]
#define OFF_ZQ4    1408512     // u64 pairs [11][4][256] (layer0 uses slots 0,1)
#define OFF_XQ     1431040     // u64 pairs [11][256]    (x_j from Q0, j=1..10)
#define OFF_IDXQ   1436672     // one u64 pair
#define WS_FLOATS  1436736

#define FBAR(r)  (32*(r))      // init barriers; poison-safe monotone

// ---- agent-scope plain relaxed prims (proven coherence class) -------------
__device__ __forceinline__ float ldc(const float* p) {
  int v = __hip_atomic_load((const int*)p, __ATOMIC_RELAXED, __HIP_MEMORY_SCOPE_AGENT);
  return __int_as_float(v);
}
__device__ __forceinline__ void stc(float* p, float x) {
  __hip_atomic_store((int*)p, __float_as_int(x), __ATOMIC_RELAXED, __HIP_MEMORY_SCOPE_AGENT);
}
__device__ __forceinline__ u64 ldq(const u64* p) {
  return __hip_atomic_load(p, __ATOMIC_RELAXED, __HIP_MEMORY_SCOPE_AGENT);
}
__device__ __forceinline__ void stq(u64* p, float v, int tag) {
  u64 x = (u64)(unsigned)__float_as_int(v) | ((u64)(unsigned)tag << 32);
  __hip_atomic_store(p, x, __ATOMIC_RELAXED, __HIP_MEMORY_SCOPE_AGENT);
}
__device__ __forceinline__ int ptag(u64 q) { return (int)(q >> 32); }
__device__ __forceinline__ float pval(u64 q) { return __int_as_float((int)(unsigned)q); }

// ---- R13-proven fixed pre-sleep: ~10.2us of the ~21us dead wait -----------
__device__ __forceinline__ void presleep() {
  __builtin_amdgcn_s_sleep(127);   // ~3.4us each at 2.4GHz
  __builtin_amdgcn_s_sleep(127);
  __builtin_amdgcn_s_sleep(127);
}

// ---- R9 single-outstanding spins (proven class) ---------------------------
__device__ __forceinline__ float spin_pair(const u64* p, int want) {
  int bud = 1 << 20; u64 q;
  do { q = ldq(p); } while (ptag(q) < want && --bud > 0);
  return pval(q);
}
__device__ __forceinline__ int spin_idx(const u64* p, int want) {
  int bud = 1 << 20; u64 q;
  do { q = ldq(p); } while (ptag(q) < want && --bud > 0);
  return __float_as_int(pval(q)) & 255;
}
__device__ __forceinline__ void spin2(const u64* p1, const u64* p2, int want,
                                      float& v1, float& v2) {
  int bud = 1 << 20; u64 q1, q2; bool ok;
  do {
    q1 = ldq(p1); q2 = ldq(p2);
    ok = (ptag(q1) >= want) & (ptag(q2) >= want);
  } while (!ok && --bud > 0);
  v1 = pval(q1); v2 = pval(q2);
}
__device__ __forceinline__ void spin5(const u64* p0, const u64* p1, const u64* p2,
                                      const u64* p3, const u64* p4, int want,
                                      float& v0, float& v1, float& v2, float& v3, float& v4) {
  int bud = 1 << 20; u64 q0, q1, q2, q3, q4; bool ok;
  do {
    q0 = ldq(p0); q1 = ldq(p1); q2 = ldq(p2); q3 = ldq(p3); q4 = ldq(p4);
    ok = (ptag(q0) >= want) & (ptag(q1) >= want) & (ptag(q2) >= want)
       & (ptag(q3) >= want) & (ptag(q4) >= want);
  } while (!ok && --bud > 0);
  v0 = pval(q0); v1 = pval(q1); v2 = pval(q2); v3 = pval(q3); v4 = pval(q4);
}
__device__ __forceinline__ void spin_tag2(const u64* p1, const u64* p2, int w1, int w2) {
  int bud = 1 << 18; u64 q1, q2; bool ok;
  do {
    q1 = ldq(p1); q2 = ldq(p2);
    ok = (ptag(q1) >= w1) & (ptag(q2) >= w2);
    if (!ok) __builtin_amdgcn_s_sleep(31);   // proven R13 helper nap
  } while (!ok && --bud > 0);
}
// init-phase flag prims (proven)
__device__ __forceinline__ void wait1(int* f, int want) {
  int it = 0;
  while (__hip_atomic_load(f, __ATOMIC_RELAXED, __HIP_MEMORY_SCOPE_AGENT) < want) {
    if (++it > (1 << 22)) break;
  }
  (void)__hip_atomic_load(f, __ATOMIC_ACQUIRE, __HIP_MEMORY_SCOPE_AGENT);
}
__device__ __forceinline__ void post(int* f, int v) {
  __hip_atomic_store(f, v, __ATOMIC_RELEASE, __HIP_MEMORY_SCOPE_AGENT);
}

__global__ __launch_bounds__(512, 1)
void fftnet_kernel(const float* __restrict__ y, const float* __restrict__ samples,
                   const float* __restrict__ emb_raw, const float* __restrict__ condW,
                   const float* __restrict__ WV_past, const float* __restrict__ WV_present,
                   const float* __restrict__ W_o_w, const float* __restrict__ W_o_b,
                   const float* __restrict__ end_w, const float* __restrict__ end_b,
                   int* __restrict__ out, float* __restrict__ ws)
{
  const int tid = threadIdx.x;
  const int bid = blockIdx.x;
  int* iflags = (int*)(ws + WS_FLOATS);
  u64* zq4  = (u64*)(ws + OFF_ZQ4);
  u64* xq   = (u64*)(ws + OFF_XQ);
  u64* tq   = (u64*)(ws + OFF_TAPQ);
  u64* idxq = (u64*)(ws + OFF_IDXQ);

  __shared__ float s_x[256];
  __shared__ float s_xp[4 * 72];     // padded x staging: stride 72 = 8 mod 32
  __shared__ float s_h[256];
  __shared__ float s_p[1024];
  __shared__ float s_cond[2048];
  __shared__ float s_tap[64];
  __shared__ float s_m[320];
  __shared__ unsigned long long s_mask[8];

  // ---- init B: embt = tanh(emb_raw) ---------------------------------------
  for (int i = bid * 512 + tid; i < 65536; i += NBLK * 512)
    stc(ws + OFF_EMBT + i, tanhf(emb_raw[i]));
  __syncthreads();
  if (tid == 0) post(iflags + FBAR(bid), 1);
  if (tid < NBLK) wait1(iflags + FBAR(tid), 1);
  __syncthreads();

  // ---- init C: WPEt / WVP0Et tables ---------------------------------------
  for (int n = bid; n < 512; n += NBLK) {
    const float* wmat = (n < 256) ? WV_present : WV_past;  // layer-0 slice
    int cls = n & 255;
    int c = tid & 255, s2 = tid >> 8;
    float acc = 0.f;
    for (int k = 128 * s2; k < 128 * s2 + 128; ++k)
      acc += wmat[c * 256 + k] * ws[OFF_EMBT + cls * 256 + k];
    s_p[s2 * 256 + c] = acc;
    __syncthreads();
    if (tid < 256)
      stc(ws + ((n < 256) ? OFF_WPET : OFF_WVPET) + cls * 256 + tid, s_p[tid] + s_p[256 + tid]);
    __syncthreads();
  }
  __syncthreads();
  if (tid == 0) post(iflags + FBAR(bid), 2);
  if (tid < NBLK) wait1(iflags + FBAR(tid), 2);
  __syncthreads();
  __builtin_amdgcn_fence(__ATOMIC_ACQUIRE, "agent");   // invalidate stale L1
  __syncthreads();

  // =========================================================================
  if (bid == 0) {
    // ------------------------- sampler -------------------------------------
    const int c = tid & 255, s2 = tid >> 8;
    v64f we0;                               // first 64: register-resident
#pragma unroll
    for (int i = 0; i < 64; ++i) we0[i] = end_w[c * 256 + 128 * s2 + i];
    const float eb = end_b[c];
    const float b10 = W_o_b[10 * 256 + c];
    const u64* pz0 = zq4 + (10 * 4 + 0) * 256;
    const u64* pz1 = zq4 + (10 * 4 + 1) * 256;
    const u64* pz2 = zq4 + (10 * 4 + 2) * 256;
    const u64* pz3 = zq4 + (10 * 4 + 3) * 256;
    const u64* pxq = xq + 10 * 256;
    const int lane = tid & 63, w = tid >> 6;
    if (tid == 0) stq(idxq, __int_as_float(127), 1);

    for (int t = 0; t < T_STEPS; ++t) {
      float u = samples[t];
      // we1 prefetch (R12): issue before the sleep+spin so the L2 stream
      // completes during the dead wait.
      const float* ewp = end_w + c * 256 + 128 * s2 + 64;
      asm volatile("" : "+v"(ewp));
      ewp = (const float*)__builtin_assume_aligned(ewp, 16);
      v64f we1;
#pragma unroll
      for (int i = 0; i < 64; ++i) we1[i] = ewp[i];
      __builtin_amdgcn_sched_barrier(0);

      if (tid < 256) {
        if (t >= 2) presleep();             // ~10.2us of the ~21us dead wait
        float a, b, cc, d, r3;
        spin5(pz0 + tid, pz1 + tid, pz2 + tid, pz3 + tid, pxq + tid, t + 1, a, b, cc, d, r3);
        float s01 = a + b, s23 = cc + d;          // == zA, zB of R7 bitwise
        s_x[tid] = fmaxf(s01 + s23 + b10 + r3, 0.f);
      }
      __syncthreads();
      float acc = 0.f;
#pragma unroll
      for (int i = 0; i < 64; ++i) acc += we0[i] * s_x[128 * s2 + i];
#pragma unroll
      for (int i = 0; i < 64; ++i) acc += we1[i] * s_x[128 * s2 + 64 + i];
      s_p[s2 * 256 + c] = acc;
      __syncthreads();
      float logit = 0.f;
      if (tid < 256) logit = s_p[tid] + s_p[256 + tid] + eb;
      float vmax = (tid < 256) ? logit : -3.4e38f;
#pragma unroll
      for (int d2 = 32; d2 > 0; d2 >>= 1) vmax = fmaxf(vmax, __shfl_xor(vmax, d2, 64));
      if (lane == 0) s_m[280 + w] = vmax;
      __syncthreads();
      float mx = fmaxf(fmaxf(s_m[280], s_m[281]), fmaxf(s_m[282], s_m[283]));
      float e = (tid < 256) ? expf(logit - mx) : 0.f;
      float vs = e;
#pragma unroll
      for (int d2 = 32; d2 > 0; d2 >>= 1) vs += __shfl_xor(vs, d2, 64);
      if (lane == 0) s_m[288 + w] = vs;
      __syncthreads();
      float ssum = s_m[288] + s_m[289] + s_m[290] + s_m[291];
      float p = (tid < 256) ? (e / ssum) : 0.f;
      float v = p;
#pragma unroll
      for (int d2 = 1; d2 < 64; d2 <<= 1) {
        float o = __shfl_up(v, (unsigned)d2, 64);
        if (lane >= d2) v += o;
      }
      if (tid < 256 && lane == 63) s_m[256 + w] = v;
      __syncthreads();
      float offs = 0.f;
      if (tid < 256) for (int k = 0; k < w; ++k) offs += s_m[256 + k];
      float cum = v + offs;
      unsigned long long msk = __ballot(tid < 256 && (cum > u));
      if (lane == 0) s_mask[w] = msk;
      __syncthreads();
      if (tid == 0) {
        int idx = 0;
        for (int k = 0; k < 4; ++k) {
          unsigned long long m2 = s_mask[k];
          if (m2) { idx = k * 64 + (int)__builtin_ctzll(m2); break; }
        }
        stq(idxq, __int_as_float(idx), t + 2);
        out[t] = idx;
      }
      __syncthreads();
    }

  } else if (bid <= 2) {
    // ------------------------- L0A / L0B ------------------------------------
    // Fused (R15, kept): row's 2 chunk partials in adjacent lanes; 1 shfl,
    // exact order (p0+p1). 2-way LDS aliasing on s_h reads is free (m136).
    const int side = bid - 1;              // 0: h[0:128), wo cols 0:128; 1: rest
    const int row = tid >> 1, chunk = tid & 1;
    v64f wv;
#pragma unroll
    for (int i = 0; i < 64; ++i)
      wv[i] = W_o_w[row * 256 + side * 128 + chunk * 64 + i];
    for (int e = tid; e < 2048; e += 512) {
      int f = e >> 7, rr = e & 127;
      float a = 0.f;
      for (int q = 0; q < 80; ++q) a += condW[(side * 128 + rr) * 80 + q] * y[q * 16 + f];
      s_cond[f * 128 + rr] = a;
    }
    __syncthreads();
    u64* zout = zq4 + (0 * 4 + side) * 256;
    int pidx = 127;                        // tid<128 only

    for (int t = 0; t < T_STEPS; ++t) {
      if (tid < 128) {
        float tapv = (t > 0) ? ws[OFF_WVPET + pidx * 256 + side * 128 + tid] : 0.f;
        if (t >= 2) presleep();
        int idx = spin_idx(idxq, t + 1);
        float hv = s_cond[(t >> 7) * 128 + tid]
                 + ws[OFF_WPET + idx * 256 + side * 128 + tid] + tapv;
        s_h[tid] = fmaxf(hv, 0.f);
        pidx = idx;
      }
      __syncthreads();
      float acc = 0.f;
#pragma unroll
      for (int i = 0; i < 64; ++i) acc += wv[i] * s_h[64 * chunk + i];
      {
        int lb = (tid & 63) & ~1;
        float o = __shfl(acc, lb + 1, 64);
        if (chunk == 0) stq(zout + row, acc + o, t + 1);  // == s_p[tid]+s_p[256+tid]
      }
      __syncthreads();
    }

  } else if (bid <= 42) {
    // ------------------------- layer Qk (j = 1..10, k = 0..3) ---------------
    // Fused wp-dot (r=tid>>2, s=tid&3) with PADDED x staging: s_xp stride 72
    // -> reader banks (8s+i)%32 distinct -> conflict-free. Combine via 3 shfl
    // in exact left-fold ((p0+p1)+p2)+p3. 3 barriers/step.
    const int jj = 1 + ((bid - 3) >> 2);
    const int k  = (bid - 3) & 3;
    v64f wv;                                // wp frag (t<256) or wo frag (t>=256)
    if (tid < 256) {
      int r = tid >> 2, s = tid & 3;
#pragma unroll
      for (int i = 0; i < 64; ++i)
        wv[i] = WV_present[jj * 65536 + (64 * k + r) * 256 + 64 * s + i];
    } else {
      int row = tid - 256;
#pragma unroll
      for (int i = 0; i < 64; ++i)
        wv[i] = W_o_w[jj * 65536 + row * 256 + 64 * k + i];
    }
    const float bprev = W_o_b[(jj - 1) * 256 + (tid & 255)];
    for (int e = tid; e < 1024; e += 512) {
      int f = e >> 6, rr = e & 63;
      float a = 0.f;
      for (int q = 0; q < 80; ++q)
        a += condW[(jj * 256 + 64 * k + rr) * 80 + q] * y[q * 16 + f];
      s_cond[f * 64 + rr] = a;
    }
    __syncthreads();
    const int dj = 1 << jj, maskj = 2 * dj - 1;
    float* ringj = ws + OFF_RINGS + 512 * (dj - 1);
    const u64* pz0 = zq4 + ((jj - 1) * 4 + 0) * 256;
    const u64* pz1 = zq4 + ((jj - 1) * 4 + 1) * 256;
    const u64* pz2 = zq4 + ((jj - 1) * 4 + 2) * 256;
    const u64* pz3 = zq4 + ((jj - 1) * 4 + 3) * 256;
    const u64* pxp = xq + (jj - 1) * 256;
    u64* zout = zq4 + (jj * 4 + k) * 256;
    u64* xout = xq + jj * 256;
    const u64* ptap = tq + (jj - 1) * 32 * 256;

    for (int t = 0; t < T_STEPS; ++t) {
      const int want = t + 1;
      if (tid < 256) {
        float xv;
        if (t >= 2) presleep();
        if (jj == 1) {
          // idx long-published -> near-instant; issue EMBT gather, then wait
          // on the z pair (gather hides under z-wait).
          int idx = spin_idx(idxq, want);
          float ev = ws[OFF_EMBT + idx * 256 + tid];
          float a, b;
          spin2(pz0 + tid, pz1 + tid, want, a, b);
          // x1 = relu((zA0+zB0) + b0 + emb[idx]) — same association as R9
          xv = fmaxf((a + b) + bprev + ev, 0.f);
        } else {
          float a, b, cc, d, xp;
          spin5(pz0 + tid, pz1 + tid, pz2 + tid, pz3 + tid, pxp + tid, want,
                a, b, cc, d, xp);
          float s01 = a + b, s23 = cc + d;   // == zA, zB bitwise
          xv = fmaxf(s01 + s23 + bprev + xp, 0.f);
        }
        s_xp[(tid >> 6) * 72 + (tid & 63)] = xv;   // padded stage, banks 8w+l
        if (k == 0) stq(xout + tid, xv, want);     // early x publish
      } else if (tid >= 384 && tid < 448) {
        int l = tid - 384;
        s_tap[l] = spin_pair(ptap + (t & 31) * 256 + 64 * k + l, want);
      }
      __syncthreads();
      if (tid < 256) {
        int r = tid >> 2, s = tid & 3;
        float acc = 0.f;
#pragma unroll
        for (int i = 0; i < 64; ++i) acc += wv[i] * s_xp[72 * s + i];
        int lb = (tid & 63) & ~3;
        float p1 = __shfl(acc, lb + 1, 64);
        float p2 = __shfl(acc, lb + 2, 64);
        float p3 = __shfl(acc, lb + 3, 64);
        if (s == 0) {
          // ((p0+p1)+p2)+p3 + cond + tap — exact old phase-C association
          float hv = ((acc + p1) + p2) + p3
                   + s_cond[(t >> 7) * 64 + r] + s_tap[r];
          s_h[r] = fmaxf(hv, 0.f);
        }
      } else if (k == 0) {
        int row = tid - 256;
        stc(ringj + (t & maskj) * 256 + row,
            s_xp[(row >> 6) * 72 + (row & 63)]);   // x_j history for taps
      }
      __syncthreads();
      if (tid >= 256) {
        int row = tid - 256;
        float acc = 0.f;
#pragma unroll
        for (int i = 0; i < 64; ++i) acc += wv[i] * s_h[i];
        if (k == 0)
          __builtin_amdgcn_fence(__ATOMIC_RELEASE, "agent");  // ring before z tag
        stq(zout + row, acc, want);
      }
      __syncthreads();
    }

  } else {
    // ------------------------- tap helpers (j = 1..10) ----------------------
    const int j = bid - 42;
    const int dj = 1 << j, maskj = 2 * dj - 1;
    v64f wq0, wq1;
    { int r = tid & 255, s2 = tid >> 8;
#pragma unroll
      for (int i = 0; i < 64; ++i) wq0[i] = WV_past[j * 65536 + r * 256 + 128 * s2 + i];
#pragma unroll
      for (int i = 0; i < 64; ++i) wq1[i] = WV_past[j * 65536 + r * 256 + 128 * s2 + 64 + i]; }
    float* ringj = ws + OFF_RINGS + 512 * (dj - 1);
    u64* tapj = tq + (j - 1) * 32 * 256;
    const u64* z0 = zq4 + (j * 4 + 0) * 256;

    for (int t = 0; t < T_STEPS; ++t) {
      // gates: ring(t-dj) visible via z_{j,0} tag (fence-ordered, same thread);
      // slot reuse: consumer Q_{e>>6} past step t-32 via its zout tag.
      int g0 = t - 31;
      if (t >= dj && t - dj + 1 > g0) g0 = t - dj + 1;
      int gk = t - 31;
      if (tid < 256 && (g0 >= 1 || gk >= 1)) {
        const u64* zk = zq4 + (j * 4 + (tid >> 6)) * 256;
        spin_tag2(z0 + tid, zk + tid, g0, gk);
      }
      float tapv = 0.f;
      if (t >= dj) {
        if (tid < 256) s_x[tid] = ldc(ringj + ((t - dj) & maskj) * 256 + tid);
        __syncthreads();
        int r = tid & 255, s2 = tid >> 8;
        float acc = 0.f;
#pragma unroll
        for (int i = 0; i < 64; ++i) acc += wq0[i] * s_x[128 * s2 + i];
#pragma unroll
        for (int i = 0; i < 64; ++i) acc += wq1[i] * s_x[128 * s2 + 64 + i];
        s_p[s2 * 256 + r] = acc;
        __syncthreads();
        if (tid < 256) tapv = s_p[tid] + s_p[256 + tid];
      }
      if (tid < 256) stq(tapj + (t & 31) * 256 + tid, tapv, t + 1);
      __syncthreads();
    }
  }
}

extern "C" void kernel_launch(void* const* d_in, const int* in_sizes, int n_in,
                              void* d_out, int out_size, void* d_ws, size_t ws_size,
                              hipStream_t stream) {
  const float* y       = (const float*)d_in[0];
  const float* samples = (const float*)d_in[1];
  const float* emb_raw = (const float*)d_in[2];
  const float* condW   = (const float*)d_in[3];
  const float* WV_past = (const float*)d_in[4];
  const float* WV_pres = (const float*)d_in[5];
  const float* W_o_w   = (const float*)d_in[6];
  const float* W_o_b   = (const float*)d_in[7];
  const float* end_w   = (const float*)d_in[8];
  const float* end_b   = (const float*)d_in[9];
  (void)in_sizes; (void)n_in; (void)out_size; (void)ws_size;
  hipLaunchKernelGGL(fftnet_kernel, dim3(NBLK), dim3(512), 0, stream,
                     y, samples, emb_raw, condW, WV_past, WV_pres,
                     W_o_w, W_o_b, end_w, end_b, (int*)d_out, (float*)d_ws);
}